// Round 12
// baseline (200.886 us; speedup 1.0000x reference)
//
#include <hip/hip_runtime.h>
#include <hip/hip_bf16.h>

#define FIN   256
#define HF    256      // H*F
#define NCOL  512      // proj cols + skip cols
#define HEADS 8
#define FDIM  32
#define L2E   1.44269504f
#define BCAP  64       // bucket slots per node (deg ~ Poisson(16))
#define NBB   256      // bucket-build blocks (dispatched FIRST)

typedef float f32x4 __attribute__((ext_vector_type(4)));
typedef __bf16 bf16x8 __attribute__((ext_vector_type(8)));
typedef unsigned short u16x8 __attribute__((ext_vector_type(8)));

__device__ __forceinline__ unsigned short f2bf(float f) {
  unsigned u = __float_as_uint(f);
  u = u + 0x7FFFu + ((u >> 16) & 1u);   // round-to-nearest-even
  return (unsigned short)(u >> 16);
}
__device__ __forceinline__ float bf2f(unsigned short s) {
  return __uint_as_float(((unsigned)s) << 16);
}
// hardware packed f32->bf16 (RNE): D[15:0]=cvt(a), D[31:16]=cvt(b)
__device__ __forceinline__ unsigned cvt_pk_bf16(float a, float b) {
  unsigned r;
  asm("v_cvt_pk_bf16_f32 %0, %1, %2" : "=v"(r) : "v"(a), "v"(b));
  return r;
}
// async global->LDS, 16B per lane; LDS dest = wave-uniform base + lane*16
__device__ __forceinline__ void gload_lds16(const unsigned short* g, unsigned short* l) {
  __builtin_amdgcn_global_load_lds(
      (const __attribute__((address_space(1))) void*)g,
      (__attribute__((address_space(3))) void*)l,
      16, 0, 0);
}

// ---- prep: WT[col][k] bf16 from W|skip_W (tiny, serial) ----
__global__ void k_prep(const float* __restrict__ W, const float* __restrict__ SW,
                       unsigned short* __restrict__ WT) {
  int tid = blockIdx.x * 256 + threadIdx.x;
  int c = tid >> 8, k = tid & 255;
  float v = (c < HF) ? W[(size_t)k * HF + c] : SW[(size_t)k * HF + (c - HF)];
  WT[(size_t)c * FIN + k] = f2bf(v);
}

// ---- fused: bucket CSR build (blocks 0..NBB-1, FIRST)  ||  GEMM + scores ----
__global__ __launch_bounds__(512, 2) void k_gemm(const float* __restrict__ X,
                                                 const unsigned short* __restrict__ WT,
                                                 const float* __restrict__ a_src,
                                                 const float* __restrict__ a_trg,
                                                 unsigned short* __restrict__ Pb,
                                                 float* __restrict__ ss,
                                                 float* __restrict__ st, int Nn,
                                                 const int* __restrict__ eidx,
                                                 int* __restrict__ cnt,
                                                 int* __restrict__ bucket,
                                                 int E) {
  __shared__ __align__(16) unsigned short As[128 * 32];  // [row][k]  8KB
  __shared__ __align__(16) unsigned short Bs[512 * 32];  // [col][k] 32KB
  if (blockIdx.x < NBB) {
    // ---- bucket-build role: one-pass CSR into fixed-stride buckets ----
    for (int e = blockIdx.x * 512 + threadIdx.x; e < E; e += NBB * 512) {
      int trg = eidx[E + e];
      int pos = atomicAdd(&cnt[trg], 1);
      if (pos < BCAP) bucket[((unsigned)trg << 6) + pos] = eidx[e];
    }
    return;
  }
  const int t = threadIdx.x;
  const int bm0 = (blockIdx.x - NBB) * 128;
  const int lane = t & 63, wid = t >> 6;
  const int wm = wid >> 2, wn = wid & 3;      // 2 x 4 wave grid
  const int lo = lane & 15, g = lane >> 4;
  const int swz = (lo >> 2) & 3;              // read-side XOR term
  f32x4 acc[4][8];
#pragma unroll
  for (int i = 0; i < 4; ++i)
#pragma unroll
    for (int j = 0; j < 8; ++j) acc[i][j] = (f32x4){0.f, 0.f, 0.f, 0.f};

  const int arow = t >> 2, aseg0 = t & 3;
  const int aq = aseg0 ^ ((t >> 4) & 3);      // swizzled A quad slot
  int grow = bm0 + arow; if (grow > Nn - 1) grow = Nn - 1;
  const float* xsrc = X + (size_t)grow * FIN + aseg0 * 8;
  unsigned short* adst = As + arow * 32 + aq * 8;
  // async B staging: lane l covers subtile row l>>2, dest quad l (linear);
  // source k-seg pre-swizzled so LDS position matches read-side XOR.
  const int bcol = lane >> 2;
  const int bseg = (lane & 3) ^ ((lane >> 4) & 3);

  for (int kk = 0; kk < FIN; kk += 32) {
#pragma unroll
    for (int j = 0; j < 4; ++j) {
      int cg = wid * 4 + j;                     // 16-col group 0..31
      const unsigned short* gp =
          WT + (size_t)(cg * 16 + bcol) * FIN + kk + bseg * 8;
      gload_lds16(gp, Bs + cg * 512);
    }
    float4 f0 = *(const float4*)(xsrc + kk);
    float4 f1 = *(const float4*)(xsrc + kk + 4);
    uint4 ap = {cvt_pk_bf16(f0.x, f0.y), cvt_pk_bf16(f0.z, f0.w),
                cvt_pk_bf16(f1.x, f1.y), cvt_pk_bf16(f1.z, f1.w)};
    *(uint4*)adst = ap;
    __syncthreads();
    bf16x8 a[4], b[8];
#pragma unroll
    for (int mi = 0; mi < 4; ++mi)
      a[mi] = __builtin_bit_cast(bf16x8,
          *(const u16x8*)(As + (wm * 64 + mi * 16 + lo) * 32 + ((g ^ swz) * 8)));
#pragma unroll
    for (int ni = 0; ni < 8; ++ni)
      b[ni] = __builtin_bit_cast(bf16x8,
          *(const u16x8*)(Bs + (wn * 128 + ni * 16 + lo) * 32 + ((g ^ swz) * 8)));
#pragma unroll
    for (int mi = 0; mi < 4; ++mi)
#pragma unroll
      for (int ni = 0; ni < 8; ++ni)
        acc[mi][ni] = __builtin_amdgcn_mfma_f32_16x16x32_bf16(b[ni], a[mi], acc[mi][ni], 0, 0, 0);
    __syncthreads();
  }
  // operand-swapped: acc[mi][ni][r] = P[row = wm*64+mi*16+lo][col = wn*128+ni*16+g*4+r]
#pragma unroll
  for (int mi = 0; mi < 4; ++mi) {
    int gr = bm0 + wm * 64 + mi * 16 + lo;
    if (gr < Nn) {
#pragma unroll
      for (int ni = 0; ni < 8; ++ni) {
        f32x4 v = acc[mi][ni];
        uint2 pk = {cvt_pk_bf16(v[0], v[1]), cvt_pk_bf16(v[2], v[3])};
        *(uint2*)(Pb + (size_t)gr * NCOL + wn * 128 + ni * 16 + g * 4) = pk;
      }
    }
  }
  // fused scores: waves wn=0,1 cover proj cols 0..255; heads wn*4 + (ni>>1)
  if (wn < 2) {
    float psS[4][4], psT[4][4];
#pragma unroll
    for (int mi = 0; mi < 4; ++mi)
#pragma unroll
      for (int hd = 0; hd < 4; ++hd) { psS[mi][hd] = 0.f; psT[mi][hd] = 0.f; }
    const int cbase = wn * 128 + g * 4;
#pragma unroll
    for (int ni = 0; ni < 8; ++ni) {
      float4 av = *(const float4*)(a_src + cbase + ni * 16);
      float4 tv = *(const float4*)(a_trg + cbase + ni * 16);
      int hd = ni >> 1;
#pragma unroll
      for (int mi = 0; mi < 4; ++mi) {
        f32x4 v = acc[mi][ni];
        psS[mi][hd] += v[0]*av.x + v[1]*av.y + v[2]*av.z + v[3]*av.w;
        psT[mi][hd] += v[0]*tv.x + v[1]*tv.y + v[2]*tv.z + v[3]*tv.w;
      }
    }
#pragma unroll
    for (int mi = 0; mi < 4; ++mi) {
      int gr = bm0 + wm * 64 + mi * 16 + lo;
#pragma unroll
      for (int hd = 0; hd < 4; ++hd) {
        float s = psS[mi][hd]; s += __shfl_xor(s, 16); s += __shfl_xor(s, 32);
        float tt = psT[mi][hd]; tt += __shfl_xor(tt, 16); tt += __shfl_xor(tt, 32);
        if (g == hd && gr < Nn) {
          ss[(size_t)gr * 8 + wn * 4 + hd] = s * L2E;
          st[(size_t)gr * 8 + wn * 4 + hd] = tt * L2E;
        }
      }
    }
  }
}

// ---- per-node aggregation: 64 lanes x ushort4/edge, unroll x2, inline exp2 ----
__global__ __launch_bounds__(256) void k_agg(const unsigned short* __restrict__ Pb,
    const int* __restrict__ cnt, const int* __restrict__ bucket,
    const float* __restrict__ ss, const float* __restrict__ st,
    const float* __restrict__ bias, float* __restrict__ out, int Nn) {
  int n = blockIdx.x * 4 + (threadIdx.x >> 6);
  if (n >= Nn) return;
  const int l = threadIdx.x & 63;
  const int h = l >> 3;                    // cols l*4..l*4+3, head = (l*4)/32
  const float sth = st[(unsigned)n * 8 + h];
  float a0 = 0.f, a1 = 0.f, a2 = 0.f, a3 = 0.f, dsum = 0.f;
  int cn = cnt[n]; if (cn > BCAP) cn = BCAP;
  const int* bk = bucket + ((unsigned)n << 6);
  int i = 0;
  for (; i + 1 < cn; i += 2) {
    int s0 = bk[i], s1 = bk[i + 1];
    float v0 = ss[((unsigned)s0 << 3) + h];
    float v1 = ss[((unsigned)s1 << 3) + h];
    ushort4 p0 = *(const ushort4*)(Pb + ((unsigned)s0 << 9) + (l << 2));
    ushort4 p1 = *(const ushort4*)(Pb + ((unsigned)s1 << 9) + (l << 2));
    float x0 = v0 + sth; x0 = fmaxf(x0, 0.2f * x0);
    float x1 = v1 + sth; x1 = fmaxf(x1, 0.2f * x1);
    float w0 = __builtin_amdgcn_exp2f(x0);
    float w1 = __builtin_amdgcn_exp2f(x1);
    dsum += w0 + w1;
    a0 += w0 * bf2f(p0.x) + w1 * bf2f(p1.x);
    a1 += w0 * bf2f(p0.y) + w1 * bf2f(p1.y);
    a2 += w0 * bf2f(p0.z) + w1 * bf2f(p1.z);
    a3 += w0 * bf2f(p0.w) + w1 * bf2f(p1.w);
  }
  if (i < cn) {
    int s0 = bk[i];
    float v0 = ss[((unsigned)s0 << 3) + h];
    ushort4 p0 = *(const ushort4*)(Pb + ((unsigned)s0 << 9) + (l << 2));
    float x0 = v0 + sth; x0 = fmaxf(x0, 0.2f * x0);
    float w0 = __builtin_amdgcn_exp2f(x0);
    dsum += w0;
    a0 += w0 * bf2f(p0.x); a1 += w0 * bf2f(p0.y);
    a2 += w0 * bf2f(p0.z); a3 += w0 * bf2f(p0.w);
  }
  float inv = 1.f / (dsum + 1e-16f);
  ushort4 sk = *(const ushort4*)(Pb + ((unsigned)n << 9) + HF + (l << 2));
  float4 bi = *(const float4*)(bias + (l << 2));
  float o0 = a0 * inv + bf2f(sk.x) + bi.x;
  float o1 = a1 * inv + bf2f(sk.y) + bi.y;
  float o2 = a2 * inv + bf2f(sk.z) + bi.z;
  float o3 = a3 * inv + bf2f(sk.w) + bi.w;
  o0 = o0 > 0.f ? o0 : expm1f(o0);
  o1 = o1 > 0.f ? o1 : expm1f(o1);
  o2 = o2 > 0.f ? o2 : expm1f(o2);
  o3 = o3 > 0.f ? o3 : expm1f(o3);
  float4 o = {o0, o1, o2, o3};
  *(float4*)(out + ((unsigned)n << 8) + (l << 2)) = o;
}

extern "C" void kernel_launch(void* const* d_in, const int* in_sizes, int n_in,
                              void* d_out, int out_size, void* d_ws, size_t ws_size,
                              hipStream_t stream) {
  const float* x      = (const float*)d_in[0];
  const int*   eidx   = (const int*)d_in[1];
  const float* W      = (const float*)d_in[2];
  const float* a_src  = (const float*)d_in[3];
  const float* a_trg  = (const float*)d_in[4];
  const float* skip_W = (const float*)d_in[5];
  const float* bias   = (const float*)d_in[6];
  float* out = (float*)d_out;
  const int Nn = in_sizes[0] / FIN;
  const int E  = in_sizes[1] / 2;

  char* p = (char*)d_ws;
  auto carve = [&](size_t bytes) { char* r = p; p += (bytes + 255) & ~(size_t)255; return r; };
  unsigned short* WT = (unsigned short*)carve((size_t)NCOL * FIN * 2);
  unsigned short* Pb = (unsigned short*)carve((size_t)Nn * NCOL * 2);
  float* ss   = (float*)carve((size_t)Nn * HEADS * 4);
  float* st   = (float*)carve((size_t)Nn * HEADS * 4);
  int* cnt    = (int*)carve((size_t)Nn * 4);
  int* bucket = (int*)carve((size_t)Nn * BCAP * 4);

  // zero cnt
  hipMemsetAsync(cnt, 0, (size_t)Nn * 4, stream);

  hipLaunchKernelGGL(k_prep, dim3((NCOL * FIN) / 256), dim3(256), 0, stream,
                     W, skip_W, WT);
  const int gblocks = (Nn + 127) / 128;
  hipLaunchKernelGGL(k_gemm, dim3(NBB + gblocks), dim3(512), 0, stream,
                     x, WT, a_src, a_trg, Pb, ss, st, Nn,
                     eidx, cnt, bucket, E);
  hipLaunchKernelGGL(k_agg, dim3((Nn + 3) / 4), dim3(256), 0, stream,
                     Pb, cnt, bucket, ss, st, bias, out, Nn);
}

// Round 13
// 153.622 us; speedup vs baseline: 1.3077x; 1.3077x over previous
//
#include <hip/hip_runtime.h>
#include <hip/hip_bf16.h>

#define FIN   256
#define HF    256      // H*F
#define NCOL  512      // proj cols + skip cols
#define HEADS 8
#define FDIM  32
#define L2E   1.44269504f
#define BCAP  64       // bucket slots per node (deg ~ Poisson(16))
#define NBB   256      // bucket-build blocks (dispatched LAST — r12 showed first is bad)

typedef float f32x4 __attribute__((ext_vector_type(4)));
typedef __bf16 bf16x8 __attribute__((ext_vector_type(8)));
typedef unsigned short u16x8 __attribute__((ext_vector_type(8)));

__device__ __forceinline__ unsigned short f2bf(float f) {
  unsigned u = __float_as_uint(f);
  u = u + 0x7FFFu + ((u >> 16) & 1u);   // round-to-nearest-even
  return (unsigned short)(u >> 16);
}
__device__ __forceinline__ float bf2f(unsigned short s) {
  return __uint_as_float(((unsigned)s) << 16);
}
// hardware packed f32->bf16 (RNE): D[15:0]=cvt(a), D[31:16]=cvt(b)
__device__ __forceinline__ unsigned cvt_pk_bf16(float a, float b) {
  unsigned r;
  asm("v_cvt_pk_bf16_f32 %0, %1, %2" : "=v"(r) : "v"(a), "v"(b));
  return r;
}
// async global->LDS, 16B per lane; LDS dest = wave-uniform base + lane*16
__device__ __forceinline__ void gload_lds16(const unsigned short* g, unsigned short* l) {
  __builtin_amdgcn_global_load_lds(
      (const __attribute__((address_space(1))) void*)g,
      (__attribute__((address_space(3))) void*)l,
      16, 0, 0);
}

// ---- prep: WT[col][k] bf16 from W|skip_W (tiny, serial) ----
__global__ void k_prep(const float* __restrict__ W, const float* __restrict__ SW,
                       unsigned short* __restrict__ WT) {
  int tid = blockIdx.x * 256 + threadIdx.x;
  int c = tid >> 8, k = tid & 255;
  float v = (c < HF) ? W[(size_t)k * HF + c] : SW[(size_t)k * HF + (c - HF)];
  WT[(size_t)c * FIN + k] = f2bf(v);
}

// ---- fused: GEMM + scores (blocks 0..gblocks-1)  ||  bucket CSR build (last) ----
__global__ __launch_bounds__(512, 2) void k_gemm(const float* __restrict__ X,
                                                 const unsigned short* __restrict__ WT,
                                                 const float* __restrict__ a_src,
                                                 const float* __restrict__ a_trg,
                                                 unsigned short* __restrict__ Pb,
                                                 float* __restrict__ ss,
                                                 float* __restrict__ st, int Nn,
                                                 const int* __restrict__ eidx,
                                                 int* __restrict__ cnt,
                                                 int* __restrict__ bucket,
                                                 int E, int gblocks) {
  __shared__ __align__(16) unsigned short As[128 * 32];  // [row][k]  8KB
  __shared__ __align__(16) unsigned short Bs[512 * 32];  // [col][k] 32KB
  if (blockIdx.x >= gblocks) {
    // ---- bucket-build role: one-pass CSR into fixed-stride buckets ----
    for (int e = (blockIdx.x - gblocks) * 512 + threadIdx.x; e < E; e += NBB * 512) {
      int trg = eidx[E + e];
      int pos = atomicAdd(&cnt[trg], 1);
      if (pos < BCAP) bucket[((unsigned)trg << 6) + pos] = eidx[e];
    }
    return;
  }
  const int t = threadIdx.x;
  const int bm0 = blockIdx.x * 128;
  const int lane = t & 63, wid = t >> 6;
  const int wm = wid >> 2, wn = wid & 3;      // 2 x 4 wave grid
  const int lo = lane & 15, g = lane >> 4;
  const int swz = (lo >> 2) & 3;              // read-side XOR term
  f32x4 acc[4][8];
#pragma unroll
  for (int i = 0; i < 4; ++i)
#pragma unroll
    for (int j = 0; j < 8; ++j) acc[i][j] = (f32x4){0.f, 0.f, 0.f, 0.f};

  const int arow = t >> 2, aseg0 = t & 3;
  const int aq = aseg0 ^ ((t >> 4) & 3);      // swizzled A quad slot
  int grow = bm0 + arow; if (grow > Nn - 1) grow = Nn - 1;
  const float* xsrc = X + (size_t)grow * FIN + aseg0 * 8;
  unsigned short* adst = As + arow * 32 + aq * 8;
  // async B staging: lane l covers subtile row l>>2, dest quad l (linear);
  // source k-seg pre-swizzled so LDS position matches read-side XOR.
  const int bcol = lane >> 2;
  const int bseg = (lane & 3) ^ ((lane >> 4) & 3);

  // software-pipelined X load: regs hold iteration-kk data
  float4 f0 = *(const float4*)(xsrc);
  float4 f1 = *(const float4*)(xsrc + 4);

  for (int kk = 0; kk < FIN; kk += 32) {
#pragma unroll
    for (int j = 0; j < 4; ++j) {
      int cg = wid * 4 + j;                     // 16-col group 0..31
      const unsigned short* gp =
          WT + (size_t)(cg * 16 + bcol) * FIN + kk + bseg * 8;
      gload_lds16(gp, Bs + cg * 512);
    }
    uint4 ap = {cvt_pk_bf16(f0.x, f0.y), cvt_pk_bf16(f0.z, f0.w),
                cvt_pk_bf16(f1.x, f1.y), cvt_pk_bf16(f1.z, f1.w)};
    *(uint4*)adst = ap;
    if (kk + 32 < FIN) {                        // prefetch next-iteration X
      f0 = *(const float4*)(xsrc + kk + 32);
      f1 = *(const float4*)(xsrc + kk + 36);
    }
    __syncthreads();
    bf16x8 a[4], b[8];
#pragma unroll
    for (int mi = 0; mi < 4; ++mi)
      a[mi] = __builtin_bit_cast(bf16x8,
          *(const u16x8*)(As + (wm * 64 + mi * 16 + lo) * 32 + ((g ^ swz) * 8)));
#pragma unroll
    for (int ni = 0; ni < 8; ++ni)
      b[ni] = __builtin_bit_cast(bf16x8,
          *(const u16x8*)(Bs + (wn * 128 + ni * 16 + lo) * 32 + ((g ^ swz) * 8)));
#pragma unroll
    for (int mi = 0; mi < 4; ++mi)
#pragma unroll
      for (int ni = 0; ni < 8; ++ni)
        acc[mi][ni] = __builtin_amdgcn_mfma_f32_16x16x32_bf16(b[ni], a[mi], acc[mi][ni], 0, 0, 0);
    __syncthreads();
  }
  // operand-swapped: acc[mi][ni][r] = P[row = wm*64+mi*16+lo][col = wn*128+ni*16+g*4+r]
#pragma unroll
  for (int mi = 0; mi < 4; ++mi) {
    int gr = bm0 + wm * 64 + mi * 16 + lo;
    if (gr < Nn) {
#pragma unroll
      for (int ni = 0; ni < 8; ++ni) {
        f32x4 v = acc[mi][ni];
        uint2 pk = {cvt_pk_bf16(v[0], v[1]), cvt_pk_bf16(v[2], v[3])};
        *(uint2*)(Pb + (size_t)gr * NCOL + wn * 128 + ni * 16 + g * 4) = pk;
      }
    }
  }
  // fused scores: waves wn=0,1 cover proj cols 0..255; heads wn*4 + (ni>>1)
  if (wn < 2) {
    float psS[4][4], psT[4][4];
#pragma unroll
    for (int mi = 0; mi < 4; ++mi)
#pragma unroll
      for (int hd = 0; hd < 4; ++hd) { psS[mi][hd] = 0.f; psT[mi][hd] = 0.f; }
    const int cbase = wn * 128 + g * 4;
#pragma unroll
    for (int ni = 0; ni < 8; ++ni) {
      float4 av = *(const float4*)(a_src + cbase + ni * 16);
      float4 tv = *(const float4*)(a_trg + cbase + ni * 16);
      int hd = ni >> 1;
#pragma unroll
      for (int mi = 0; mi < 4; ++mi) {
        f32x4 v = acc[mi][ni];
        psS[mi][hd] += v[0]*av.x + v[1]*av.y + v[2]*av.z + v[3]*av.w;
        psT[mi][hd] += v[0]*tv.x + v[1]*tv.y + v[2]*tv.z + v[3]*tv.w;
      }
    }
#pragma unroll
    for (int mi = 0; mi < 4; ++mi) {
      int gr = bm0 + wm * 64 + mi * 16 + lo;
#pragma unroll
      for (int hd = 0; hd < 4; ++hd) {
        float s = psS[mi][hd]; s += __shfl_xor(s, 16); s += __shfl_xor(s, 32);
        float tt = psT[mi][hd]; tt += __shfl_xor(tt, 16); tt += __shfl_xor(tt, 32);
        if (g == hd && gr < Nn) {
          ss[(size_t)gr * 8 + wn * 4 + hd] = s * L2E;
          st[(size_t)gr * 8 + wn * 4 + hd] = tt * L2E;
        }
      }
    }
  }
}

// ---- per-node aggregation: 64 lanes x ushort4/edge, unroll x2, inline exp2 ----
__global__ __launch_bounds__(256) void k_agg(const unsigned short* __restrict__ Pb,
    const int* __restrict__ cnt, const int* __restrict__ bucket,
    const float* __restrict__ ss, const float* __restrict__ st,
    const float* __restrict__ bias, float* __restrict__ out, int Nn) {
  int n = blockIdx.x * 4 + (threadIdx.x >> 6);
  if (n >= Nn) return;
  const int l = threadIdx.x & 63;
  const int h = l >> 3;                    // cols l*4..l*4+3, head = (l*4)/32
  const float sth = st[(unsigned)n * 8 + h];
  float a0 = 0.f, a1 = 0.f, a2 = 0.f, a3 = 0.f, dsum = 0.f;
  int cn = cnt[n]; if (cn > BCAP) cn = BCAP;
  const int* bk = bucket + ((unsigned)n << 6);
  int i = 0;
  for (; i + 1 < cn; i += 2) {
    int s0 = bk[i], s1 = bk[i + 1];
    float v0 = ss[((unsigned)s0 << 3) + h];
    float v1 = ss[((unsigned)s1 << 3) + h];
    ushort4 p0 = *(const ushort4*)(Pb + ((unsigned)s0 << 9) + (l << 2));
    ushort4 p1 = *(const ushort4*)(Pb + ((unsigned)s1 << 9) + (l << 2));
    float x0 = v0 + sth; x0 = fmaxf(x0, 0.2f * x0);
    float x1 = v1 + sth; x1 = fmaxf(x1, 0.2f * x1);
    float w0 = __builtin_amdgcn_exp2f(x0);
    float w1 = __builtin_amdgcn_exp2f(x1);
    dsum += w0 + w1;
    a0 += w0 * bf2f(p0.x) + w1 * bf2f(p1.x);
    a1 += w0 * bf2f(p0.y) + w1 * bf2f(p1.y);
    a2 += w0 * bf2f(p0.z) + w1 * bf2f(p1.z);
    a3 += w0 * bf2f(p0.w) + w1 * bf2f(p1.w);
  }
  if (i < cn) {
    int s0 = bk[i];
    float v0 = ss[((unsigned)s0 << 3) + h];
    ushort4 p0 = *(const ushort4*)(Pb + ((unsigned)s0 << 9) + (l << 2));
    float x0 = v0 + sth; x0 = fmaxf(x0, 0.2f * x0);
    float w0 = __builtin_amdgcn_exp2f(x0);
    dsum += w0;
    a0 += w0 * bf2f(p0.x); a1 += w0 * bf2f(p0.y);
    a2 += w0 * bf2f(p0.z); a3 += w0 * bf2f(p0.w);
  }
  float inv = 1.f / (dsum + 1e-16f);
  ushort4 sk = *(const ushort4*)(Pb + ((unsigned)n << 9) + HF + (l << 2));
  float4 bi = *(const float4*)(bias + (l << 2));
  float o0 = a0 * inv + bf2f(sk.x) + bi.x;
  float o1 = a1 * inv + bf2f(sk.y) + bi.y;
  float o2 = a2 * inv + bf2f(sk.z) + bi.z;
  float o3 = a3 * inv + bf2f(sk.w) + bi.w;
  o0 = o0 > 0.f ? o0 : expm1f(o0);
  o1 = o1 > 0.f ? o1 : expm1f(o1);
  o2 = o2 > 0.f ? o2 : expm1f(o2);
  o3 = o3 > 0.f ? o3 : expm1f(o3);
  float4 o = {o0, o1, o2, o3};
  *(float4*)(out + ((unsigned)n << 8) + (l << 2)) = o;
}

extern "C" void kernel_launch(void* const* d_in, const int* in_sizes, int n_in,
                              void* d_out, int out_size, void* d_ws, size_t ws_size,
                              hipStream_t stream) {
  const float* x      = (const float*)d_in[0];
  const int*   eidx   = (const int*)d_in[1];
  const float* W      = (const float*)d_in[2];
  const float* a_src  = (const float*)d_in[3];
  const float* a_trg  = (const float*)d_in[4];
  const float* skip_W = (const float*)d_in[5];
  const float* bias   = (const float*)d_in[6];
  float* out = (float*)d_out;
  const int Nn = in_sizes[0] / FIN;
  const int E  = in_sizes[1] / 2;

  char* p = (char*)d_ws;
  auto carve = [&](size_t bytes) { char* r = p; p += (bytes + 255) & ~(size_t)255; return r; };
  unsigned short* WT = (unsigned short*)carve((size_t)NCOL * FIN * 2);
  unsigned short* Pb = (unsigned short*)carve((size_t)Nn * NCOL * 2);
  float* ss   = (float*)carve((size_t)Nn * HEADS * 4);
  float* st   = (float*)carve((size_t)Nn * HEADS * 4);
  int* cnt    = (int*)carve((size_t)Nn * 4);
  int* bucket = (int*)carve((size_t)Nn * BCAP * 4);

  // zero cnt
  hipMemsetAsync(cnt, 0, (size_t)Nn * 4, stream);

  hipLaunchKernelGGL(k_prep, dim3((NCOL * FIN) / 256), dim3(256), 0, stream,
                     W, skip_W, WT);
  const int gblocks = (Nn + 127) / 128;
  hipLaunchKernelGGL(k_gemm, dim3(gblocks + NBB), dim3(512), 0, stream,
                     x, WT, a_src, a_trg, Pb, ss, st, Nn,
                     eidx, cnt, bucket, E, gblocks);
  hipLaunchKernelGGL(k_agg, dim3((Nn + 3) / 4), dim3(256), 0, stream,
                     Pb, cnt, bucket, ss, st, bias, out, Nn);
}

// Round 14
// 150.255 us; speedup vs baseline: 1.3370x; 1.0224x over previous
//
#include <hip/hip_runtime.h>
#include <hip/hip_bf16.h>

#define FIN   256
#define HF    256      // H*F
#define NCOL  512      // proj cols + skip cols
#define HEADS 8
#define FDIM  32
#define L2E   1.44269504f
#define BCAP  64       // bucket slots per node (deg ~ Poisson(16))
#define NBB   256      // bucket-build blocks (dispatched LAST — r12: first is bad)
#define BK    64       // K-step (2 MFMA k-substeps per staging/barrier pair)

typedef float f32x4 __attribute__((ext_vector_type(4)));
typedef __bf16 bf16x8 __attribute__((ext_vector_type(8)));
typedef unsigned short u16x8 __attribute__((ext_vector_type(8)));

__device__ __forceinline__ unsigned short f2bf(float f) {
  unsigned u = __float_as_uint(f);
  u = u + 0x7FFFu + ((u >> 16) & 1u);   // round-to-nearest-even
  return (unsigned short)(u >> 16);
}
__device__ __forceinline__ float bf2f(unsigned short s) {
  return __uint_as_float(((unsigned)s) << 16);
}
// hardware packed f32->bf16 (RNE): D[15:0]=cvt(a), D[31:16]=cvt(b)
__device__ __forceinline__ unsigned cvt_pk_bf16(float a, float b) {
  unsigned r;
  asm("v_cvt_pk_bf16_f32 %0, %1, %2" : "=v"(r) : "v"(a), "v"(b));
  return r;
}
// async global->LDS, 16B per lane; LDS dest = wave-uniform base + lane*16
__device__ __forceinline__ void gload_lds16(const unsigned short* g, unsigned short* l) {
  __builtin_amdgcn_global_load_lds(
      (const __attribute__((address_space(1))) void*)g,
      (__attribute__((address_space(3))) void*)l,
      16, 0, 0);
}

// ---- prep: WT[col][k] bf16 from W|skip_W (tiny, serial) ----
__global__ void k_prep(const float* __restrict__ W, const float* __restrict__ SW,
                       unsigned short* __restrict__ WT) {
  int tid = blockIdx.x * 256 + threadIdx.x;
  int c = tid >> 8, k = tid & 255;
  float v = (c < HF) ? W[(size_t)k * HF + c] : SW[(size_t)k * HF + (c - HF)];
  WT[(size_t)c * FIN + k] = f2bf(v);
}

// ---- fused: GEMM + scores (blocks 0..gblocks-1)  ||  bucket CSR build (last) ----
// LDS rows are 128B (BK=64 bf16). XOR swizzle: 16B-quad q stored at
// q_phys = q ^ (row&7). Applied on A-write, B-global-source, and both reads.
__global__ __launch_bounds__(512, 2) void k_gemm(const float* __restrict__ X,
                                                 const unsigned short* __restrict__ WT,
                                                 const float* __restrict__ a_src,
                                                 const float* __restrict__ a_trg,
                                                 unsigned short* __restrict__ Pb,
                                                 float* __restrict__ ss,
                                                 float* __restrict__ st, int Nn,
                                                 const int* __restrict__ eidx,
                                                 int* __restrict__ cnt,
                                                 int* __restrict__ bucket,
                                                 int E, int gblocks) {
  __shared__ __align__(16) unsigned short As[128 * BK];  // 16KB
  __shared__ __align__(16) unsigned short Bs[512 * BK];  // 64KB
  if (blockIdx.x >= gblocks) {
    // ---- bucket-build role: one-pass CSR into fixed-stride buckets ----
    for (int e = (blockIdx.x - gblocks) * 512 + threadIdx.x; e < E; e += NBB * 512) {
      int trg = eidx[E + e];
      int pos = atomicAdd(&cnt[trg], 1);
      if (pos < BCAP) bucket[((unsigned)trg << 6) + pos] = eidx[e];
    }
    return;
  }
  const int t = threadIdx.x;
  const int bm0 = blockIdx.x * 128;
  const int lane = t & 63, wid = t >> 6;
  const int wm = wid >> 2, wn = wid & 3;      // 2 x 4 wave grid
  const int lo = lane & 15, g = lane >> 4;
  const int rsw = lo & 7;                     // read-side XOR term (row&7 == lo&7)
  f32x4 acc[4][8];
#pragma unroll
  for (int i = 0; i < 4; ++i)
#pragma unroll
    for (int j = 0; j < 8; ++j) acc[i][j] = (f32x4){0.f, 0.f, 0.f, 0.f};

  // A staging: thread t -> row t>>2, ksegs 2*(t&3), 2*(t&3)+1 (8 shorts each)
  const int arow = t >> 2, ak = t & 3;
  const int aq0 = (2 * ak)     ^ (arow & 7);
  const int aq1 = (2 * ak + 1) ^ (arow & 7);
  int grow = bm0 + arow; if (grow > Nn - 1) grow = Nn - 1;
  const float* xsrc = X + (size_t)grow * FIN + ak * 16;
  // B staging: wave wid covers cols wid*64..+64; instr j: 8 cols x full 128B row.
  // lane l -> col +(l>>3), physical quad l&7; source kseg = (l&7)^((l>>3)&7).
  const int brow = lane >> 3;
  const int bksg = (lane & 7) ^ (brow & 7);

  // prefetch X for kk=0
  float4 f0 = *(const float4*)(xsrc);
  float4 f1 = *(const float4*)(xsrc + 4);
  float4 f2 = *(const float4*)(xsrc + 8);
  float4 f3 = *(const float4*)(xsrc + 12);

  for (int kk = 0; kk < FIN; kk += BK) {
#pragma unroll
    for (int j = 0; j < 8; ++j) {
      int col = wid * 64 + j * 8 + brow;
      const unsigned short* gp = WT + (size_t)col * FIN + kk + bksg * 8;
      gload_lds16(gp, Bs + (wid * 64 + j * 8) * BK);
    }
    uint4 ap0 = {cvt_pk_bf16(f0.x, f0.y), cvt_pk_bf16(f0.z, f0.w),
                 cvt_pk_bf16(f1.x, f1.y), cvt_pk_bf16(f1.z, f1.w)};
    uint4 ap1 = {cvt_pk_bf16(f2.x, f2.y), cvt_pk_bf16(f2.z, f2.w),
                 cvt_pk_bf16(f3.x, f3.y), cvt_pk_bf16(f3.z, f3.w)};
    *(uint4*)(As + arow * BK + aq0 * 8) = ap0;
    *(uint4*)(As + arow * BK + aq1 * 8) = ap1;
    if (kk + BK < FIN) {                        // prefetch next-iteration X
      f0 = *(const float4*)(xsrc + kk + BK);
      f1 = *(const float4*)(xsrc + kk + BK + 4);
      f2 = *(const float4*)(xsrc + kk + BK + 8);
      f3 = *(const float4*)(xsrc + kk + BK + 12);
    }
    __syncthreads();
#pragma unroll
    for (int ks = 0; ks < 2; ++ks) {
      bf16x8 a[4], b[8];
#pragma unroll
      for (int mi = 0; mi < 4; ++mi) {
        int row = wm * 64 + mi * 16 + lo;
        a[mi] = __builtin_bit_cast(bf16x8,
            *(const u16x8*)(As + row * BK + (((ks * 4 + g) ^ rsw) * 8)));
      }
#pragma unroll
      for (int ni = 0; ni < 8; ++ni) {
        int col = wn * 128 + ni * 16 + lo;
        b[ni] = __builtin_bit_cast(bf16x8,
            *(const u16x8*)(Bs + col * BK + (((ks * 4 + g) ^ rsw) * 8)));
      }
#pragma unroll
      for (int mi = 0; mi < 4; ++mi)
#pragma unroll
        for (int ni = 0; ni < 8; ++ni)
          acc[mi][ni] = __builtin_amdgcn_mfma_f32_16x16x32_bf16(b[ni], a[mi], acc[mi][ni], 0, 0, 0);
    }
    __syncthreads();
  }
  // operand-swapped: acc[mi][ni][r] = P[row = wm*64+mi*16+lo][col = wn*128+ni*16+g*4+r]
#pragma unroll
  for (int mi = 0; mi < 4; ++mi) {
    int gr = bm0 + wm * 64 + mi * 16 + lo;
    if (gr < Nn) {
#pragma unroll
      for (int ni = 0; ni < 8; ++ni) {
        f32x4 v = acc[mi][ni];
        uint2 pk = {cvt_pk_bf16(v[0], v[1]), cvt_pk_bf16(v[2], v[3])};
        *(uint2*)(Pb + (size_t)gr * NCOL + wn * 128 + ni * 16 + g * 4) = pk;
      }
    }
  }
  // fused scores: waves wn=0,1 cover proj cols 0..255; heads wn*4 + (ni>>1)
  if (wn < 2) {
    float psS[4][4], psT[4][4];
#pragma unroll
    for (int mi = 0; mi < 4; ++mi)
#pragma unroll
      for (int hd = 0; hd < 4; ++hd) { psS[mi][hd] = 0.f; psT[mi][hd] = 0.f; }
    const int cbase = wn * 128 + g * 4;
#pragma unroll
    for (int ni = 0; ni < 8; ++ni) {
      float4 av = *(const float4*)(a_src + cbase + ni * 16);
      float4 tv = *(const float4*)(a_trg + cbase + ni * 16);
      int hd = ni >> 1;
#pragma unroll
      for (int mi = 0; mi < 4; ++mi) {
        f32x4 v = acc[mi][ni];
        psS[mi][hd] += v[0]*av.x + v[1]*av.y + v[2]*av.z + v[3]*av.w;
        psT[mi][hd] += v[0]*tv.x + v[1]*tv.y + v[2]*tv.z + v[3]*tv.w;
      }
    }
#pragma unroll
    for (int mi = 0; mi < 4; ++mi) {
      int gr = bm0 + wm * 64 + mi * 16 + lo;
#pragma unroll
      for (int hd = 0; hd < 4; ++hd) {
        float s = psS[mi][hd]; s += __shfl_xor(s, 16); s += __shfl_xor(s, 32);
        float tt = psT[mi][hd]; tt += __shfl_xor(tt, 16); tt += __shfl_xor(tt, 32);
        if (g == hd && gr < Nn) {
          ss[(size_t)gr * 8 + wn * 4 + hd] = s * L2E;
          st[(size_t)gr * 8 + wn * 4 + hd] = tt * L2E;
        }
      }
    }
  }
}

// ---- per-node aggregation: 64 lanes x ushort4/edge, unroll x2, inline exp2 ----
__global__ __launch_bounds__(256) void k_agg(const unsigned short* __restrict__ Pb,
    const int* __restrict__ cnt, const int* __restrict__ bucket,
    const float* __restrict__ ss, const float* __restrict__ st,
    const float* __restrict__ bias, float* __restrict__ out, int Nn) {
  int n = blockIdx.x * 4 + (threadIdx.x >> 6);
  if (n >= Nn) return;
  const int l = threadIdx.x & 63;
  const int h = l >> 3;                    // cols l*4..l*4+3, head = (l*4)/32
  const float sth = st[(unsigned)n * 8 + h];
  float a0 = 0.f, a1 = 0.f, a2 = 0.f, a3 = 0.f, dsum = 0.f;
  int cn = cnt[n]; if (cn > BCAP) cn = BCAP;
  const int* bk = bucket + ((unsigned)n << 6);
  int i = 0;
  for (; i + 1 < cn; i += 2) {
    int s0 = bk[i], s1 = bk[i + 1];
    float v0 = ss[((unsigned)s0 << 3) + h];
    float v1 = ss[((unsigned)s1 << 3) + h];
    ushort4 p0 = *(const ushort4*)(Pb + ((unsigned)s0 << 9) + (l << 2));
    ushort4 p1 = *(const ushort4*)(Pb + ((unsigned)s1 << 9) + (l << 2));
    float x0 = v0 + sth; x0 = fmaxf(x0, 0.2f * x0);
    float x1 = v1 + sth; x1 = fmaxf(x1, 0.2f * x1);
    float w0 = __builtin_amdgcn_exp2f(x0);
    float w1 = __builtin_amdgcn_exp2f(x1);
    dsum += w0 + w1;
    a0 += w0 * bf2f(p0.x) + w1 * bf2f(p1.x);
    a1 += w0 * bf2f(p0.y) + w1 * bf2f(p1.y);
    a2 += w0 * bf2f(p0.z) + w1 * bf2f(p1.z);
    a3 += w0 * bf2f(p0.w) + w1 * bf2f(p1.w);
  }
  if (i < cn) {
    int s0 = bk[i];
    float v0 = ss[((unsigned)s0 << 3) + h];
    ushort4 p0 = *(const ushort4*)(Pb + ((unsigned)s0 << 9) + (l << 2));
    float x0 = v0 + sth; x0 = fmaxf(x0, 0.2f * x0);
    float w0 = __builtin_amdgcn_exp2f(x0);
    dsum += w0;
    a0 += w0 * bf2f(p0.x); a1 += w0 * bf2f(p0.y);
    a2 += w0 * bf2f(p0.z); a3 += w0 * bf2f(p0.w);
  }
  float inv = 1.f / (dsum + 1e-16f);
  ushort4 sk = *(const ushort4*)(Pb + ((unsigned)n << 9) + HF + (l << 2));
  float4 bi = *(const float4*)(bias + (l << 2));
  float o0 = a0 * inv + bf2f(sk.x) + bi.x;
  float o1 = a1 * inv + bf2f(sk.y) + bi.y;
  float o2 = a2 * inv + bf2f(sk.z) + bi.z;
  float o3 = a3 * inv + bf2f(sk.w) + bi.w;
  o0 = o0 > 0.f ? o0 : expm1f(o0);
  o1 = o1 > 0.f ? o1 : expm1f(o1);
  o2 = o2 > 0.f ? o2 : expm1f(o2);
  o3 = o3 > 0.f ? o3 : expm1f(o3);
  float4 o = {o0, o1, o2, o3};
  *(float4*)(out + ((unsigned)n << 8) + (l << 2)) = o;
}

extern "C" void kernel_launch(void* const* d_in, const int* in_sizes, int n_in,
                              void* d_out, int out_size, void* d_ws, size_t ws_size,
                              hipStream_t stream) {
  const float* x      = (const float*)d_in[0];
  const int*   eidx   = (const int*)d_in[1];
  const float* W      = (const float*)d_in[2];
  const float* a_src  = (const float*)d_in[3];
  const float* a_trg  = (const float*)d_in[4];
  const float* skip_W = (const float*)d_in[5];
  const float* bias   = (const float*)d_in[6];
  float* out = (float*)d_out;
  const int Nn = in_sizes[0] / FIN;
  const int E  = in_sizes[1] / 2;

  char* p = (char*)d_ws;
  auto carve = [&](size_t bytes) { char* r = p; p += (bytes + 255) & ~(size_t)255; return r; };
  unsigned short* WT = (unsigned short*)carve((size_t)NCOL * FIN * 2);
  unsigned short* Pb = (unsigned short*)carve((size_t)Nn * NCOL * 2);
  float* ss   = (float*)carve((size_t)Nn * HEADS * 4);
  float* st   = (float*)carve((size_t)Nn * HEADS * 4);
  int* cnt    = (int*)carve((size_t)Nn * 4);
  int* bucket = (int*)carve((size_t)Nn * BCAP * 4);

  // zero cnt
  hipMemsetAsync(cnt, 0, (size_t)Nn * 4, stream);

  hipLaunchKernelGGL(k_prep, dim3((NCOL * FIN) / 256), dim3(256), 0, stream,
                     W, skip_W, WT);
  const int gblocks = (Nn + 127) / 128;
  hipLaunchKernelGGL(k_gemm, dim3(gblocks + NBB), dim3(512), 0, stream,
                     x, WT, a_src, a_trg, Pb, ss, st, Nn,
                     eidx, cnt, bucket, E, gblocks);
  hipLaunchKernelGGL(k_agg, dim3((Nn + 3) / 4), dim3(256), 0, stream,
                     Pb, cnt, bucket, ss, st, bias, out, Nn);
}